// Round 3
// baseline (249.262 us; speedup 1.0000x reference)
//
#include <hip/hip_runtime.h>
#include <math.h>
#include <stdint.h>

// SPD encoder: out[b] = vech_triu( logm( M^T X[b] M ) ), M = W1 W2 W3 (9x3).
// ReEig clamps are provably no-ops (lambda_min >= 1e-3 > EPS=1e-4), so the
// 7x7/5x5 eigensolves vanish; only one 3x3 symmetric eig (Jacobi) per matrix.
//
// R3: persistent, barrier-free, software-pipelined streaming.
//  - 768 one-wave blocks (3/CU, LDS 41.6 KB each -> 3 co-resident), each
//    grid-strides over 64-matrix tiles (8192 tiles total).
//  - Double-buffered LDS; next tile's 21 global_load_lds are issued BEFORE
//    waiting on the current tile via asm "s_waitcnt vmcnt(21)" (FIFO: the 21
//    newest = prefetch stay in flight; older ops - current tile + previous
//    stores - drain). No __syncthreads in the loop -> no vmcnt(0) drain,
//    HBM stays saturated across tile boundaries.

#define GLOBAL_AS __attribute__((address_space(1)))
#define LDS_AS    __attribute__((address_space(3)))

__device__ __forceinline__ float fast_rcp(float x)  { return __builtin_amdgcn_rcpf(x); }
__device__ __forceinline__ float fast_rsq(float x)  { return __builtin_amdgcn_rsqf(x); }
__device__ __forceinline__ float fast_sqrt(float x) { return __builtin_amdgcn_sqrtf(x); }
__device__ __forceinline__ float fast_log(float x)  { return __builtin_amdgcn_logf(x) * 0.69314718056f; }

#define JACOBI_ROT(app, aqq, apq, arp, arq, vp0, vq0, vp1, vq1, vp2, vq2)      \
  do {                                                                         \
    float _apq = apq;                                                          \
    float _tau = (aqq - app) * 0.5f * fast_rcp(_apq);                          \
    float _t = copysignf(fast_rcp(fabsf(_tau) + fast_sqrt(fmaf(_tau, _tau, 1.f))), _tau); \
    _t = (fabsf(_apq) > 1e-20f) ? _t : 0.f;                                    \
    float _c = fast_rsq(fmaf(_t, _t, 1.f));                                    \
    float _s = _t * _c;                                                        \
    float _arp = arp, _arq = arq;                                              \
    arp = _c * _arp - _s * _arq;                                               \
    arq = _s * _arp + _c * _arq;                                               \
    app = fmaf(-_t, _apq, app);                                                \
    aqq = fmaf(_t, _apq, aqq);                                                 \
    apq = 0.f;                                                                 \
    float _v;                                                                  \
    _v = vp0; vp0 = _c * _v - _s * vq0; vq0 = _s * _v + _c * vq0;              \
    _v = vp1; vp1 = _c * _v - _s * vq1; vq1 = _s * _v + _c * vq1;              \
    _v = vp2; vp2 = _c * _v - _s * vq2; vq2 = _s * _v + _c * vq2;              \
  } while (0)

// Issue one 64-matrix tile (20736 B) global->LDS: 20x width-16 + 1x width-4.
__device__ __forceinline__ void issue_tile(const float* __restrict__ X,
                                           long long tile, float* dst, int lane)
{
    GLOBAL_AS const float* g = (GLOBAL_AS const float*)(X + tile * 5184);
    #pragma unroll
    for (int k = 0; k < 20; ++k)
        __builtin_amdgcn_global_load_lds(
            (GLOBAL_AS const void*)(g + k * 256 + lane * 4),
            (LDS_AS void*)(dst + k * 256), 16, 0, 0);
    __builtin_amdgcn_global_load_lds(
        (GLOBAL_AS const void*)(g + 5120 + lane),
        (LDS_AS void*)(dst + 5120), 4, 0, 0);
}

__global__ __launch_bounds__(64) void spd_encoder_kernel(
    const float* __restrict__ X,
    const float* __restrict__ W1,
    const float* __restrict__ W2,
    const float* __restrict__ W3,
    float* __restrict__ out,
    int ntiles)
{
    __shared__ float sX[2][5184];   // double buffer, 2 x 20736 B
    __shared__ float sM[27];        // M = W1@W2@W3, 9x3 row-major

    const int lane = threadIdx.x;   // 0..63

    // ---- M = W1(9x7)@W2(7x5)@W3(5x3), lanes 0..26 ----
    if (lane < 27) {
        const int i = lane / 3, c = lane % 3;
        float acc = 0.f;
        #pragma unroll
        for (int a = 0; a < 7; ++a) {
            float p = 0.f;
            #pragma unroll
            for (int b = 0; b < 5; ++b)
                p = fmaf(W2[a * 5 + b], W3[b * 3 + c], p);
            acc = fmaf(W1[i * 7 + a], p, acc);
        }
        sM[lane] = acc;
    }
    // Prologue-only barrier: orders sM across lanes AND drains all prior vmem
    // (W loads) so the loop's vmcnt bookkeeping starts at exactly 0.
    __syncthreads();

    float M[9][3];
    #pragma unroll
    for (int i = 0; i < 9; ++i)
        #pragma unroll
        for (int c = 0; c < 3; ++c)
            M[i][c] = sM[i * 3 + c];

    const int stride = gridDim.x;
    long long t = blockIdx.x;
    if (t >= ntiles) return;

    issue_tile(X, t, &sX[0][0], lane);   // outstanding: 21 (tile t)
    int buf = 0;

    for (; t < ntiles; t += stride) {
        // Prefetch next tile into the other buffer (dup-refetch current tile
        // on the last iteration to keep the vmcnt count uniform at 21).
        long long nt = t + stride;
        if (nt >= ntiles) nt = t;
        issue_tile(X, nt, &sX[buf ^ 1][0], lane);

        // Wait until only the 21 newest vmem ops (the prefetch) remain:
        // drains current tile's loads + previous iteration's 3 stores.
        asm volatile("s_waitcnt vmcnt(21)" ::: "memory");

        // ---- T = X * M (9x3); lane stride 81 dwords -> 2-way bank alias ----
        const float* __restrict__ x = &sX[buf][0] + lane * 81;
        float T[9][3];
        #pragma unroll
        for (int i = 0; i < 9; ++i) {
            float t0 = 0.f, t1 = 0.f, t2 = 0.f;
            #pragma unroll
            for (int j = 0; j < 9; ++j) {
                const float xv = x[i * 9 + j];
                t0 = fmaf(xv, M[j][0], t0);
                t1 = fmaf(xv, M[j][1], t1);
                t2 = fmaf(xv, M[j][2], t2);
            }
            T[i][0] = t0; T[i][1] = t1; T[i][2] = t2;
        }

        // ---- Y = M^T * T, symmetric 3x3 ----
        float A00 = 0.f, A01 = 0.f, A02 = 0.f, A11 = 0.f, A12 = 0.f, A22 = 0.f;
        #pragma unroll
        for (int i = 0; i < 9; ++i) {
            A00 = fmaf(M[i][0], T[i][0], A00);
            A01 = fmaf(M[i][0], T[i][1], A01);
            A02 = fmaf(M[i][0], T[i][2], A02);
            A11 = fmaf(M[i][1], T[i][1], A11);
            A12 = fmaf(M[i][1], T[i][2], A12);
            A22 = fmaf(M[i][2], T[i][2], A22);
        }

        // ---- Jacobi eig (5 cyclic sweeps) ----
        float V00 = 1.f, V01 = 0.f, V02 = 0.f;
        float V10 = 0.f, V11 = 1.f, V12 = 0.f;
        float V20 = 0.f, V21 = 0.f, V22 = 1.f;
        #pragma unroll
        for (int sw = 0; sw < 5; ++sw) {
            JACOBI_ROT(A00, A11, A01, A02, A12, V00, V01, V10, V11, V20, V21);
            JACOBI_ROT(A00, A22, A02, A01, A12, V00, V02, V10, V12, V20, V22);
            JACOBI_ROT(A11, A22, A12, A01, A02, V01, V02, V11, V12, V21, V22);
        }

        // ---- L = V diag(log w) V^T ----
        const float lw0 = fast_log(fmaxf(A00, 1e-12f));
        const float lw1 = fast_log(fmaxf(A11, 1e-12f));
        const float lw2 = fast_log(fmaxf(A22, 1e-12f));

        const float L00 = lw0 * V00 * V00 + lw1 * V01 * V01 + lw2 * V02 * V02;
        const float L01 = lw0 * V00 * V10 + lw1 * V01 * V11 + lw2 * V02 * V12;
        const float L02 = lw0 * V00 * V20 + lw1 * V01 * V21 + lw2 * V02 * V22;
        const float L11 = lw0 * V10 * V10 + lw1 * V11 * V11 + lw2 * V12 * V12;
        const float L12 = lw0 * V10 * V20 + lw1 * V11 * V21 + lw2 * V12 * V22;
        const float L22 = lw0 * V20 * V20 + lw1 * V21 * V21 + lw2 * V22 * V22;

        // ---- vech upper triangle: (0,0),(0,1),(0,2),(1,1),(1,2),(2,2) ----
        float2* o2 = (float2*)(out + (t * 64 + lane) * 6);  // 24B stride, 8B aligned
        o2[0] = make_float2(L00, L01);
        o2[1] = make_float2(L02, L11);
        o2[2] = make_float2(L12, L22);

        buf ^= 1;
    }
}

extern "C" void kernel_launch(void* const* d_in, const int* in_sizes, int n_in,
                              void* d_out, int out_size, void* d_ws, size_t ws_size,
                              hipStream_t stream) {
    const float* X  = (const float*)d_in[0];
    const float* W1 = (const float*)d_in[1];
    const float* W2 = (const float*)d_in[2];
    const float* W3 = (const float*)d_in[3];
    float* out = (float*)d_out;

    const int B = in_sizes[0] / 81;   // 524288
    const int ntiles = B / 64;        // 8192
    const int nblocks = 768;          // 3 one-wave blocks per CU (LDS-limited)
    spd_encoder_kernel<<<nblocks, 64, 0, stream>>>(X, W1, W2, W3, out, ntiles);
}

// Round 4
// 244.963 us; speedup vs baseline: 1.0175x; 1.0175x over previous
//
#include <hip/hip_runtime.h>
#include <math.h>
#include <stdint.h>

// SPD encoder: out[b] = vech_triu( logm( M^T X[b] M ) ), M = W1 W2 W3 (9x3).
// ReEig clamps are provably no-ops (lambda_min >= 1e-3 > EPS=1e-4) -> only a
// 3x3 symmetric eig (Jacobi) per matrix after collapsing the bimap chain.
//
// R4 (occupancy calibration): 32 matrices per one-wave block.
//  - LDS 10.4 KB/block -> 15 blocks/CU (vs 7 at the 64-matrix tile), doubling
//    wave-level fetch/compute overlap per CU.
//  - No __syncthreads at all: single-wave workgroup, ordering via one raw
//    "s_waitcnt vmcnt(0) lgkmcnt(0)" (no s_barrier drain semantics).
//  - Lanes 0-31 each own one matrix (stride-81 on 32 lanes: gcd(17,32)=1 ->
//    all 32 banks distinct, conflict-free). Lanes 32-63 stage, then idle.

#define GLOBAL_AS __attribute__((address_space(1)))
#define LDS_AS    __attribute__((address_space(3)))

__device__ __forceinline__ float fast_rcp(float x)  { return __builtin_amdgcn_rcpf(x); }
__device__ __forceinline__ float fast_rsq(float x)  { return __builtin_amdgcn_rsqf(x); }
__device__ __forceinline__ float fast_sqrt(float x) { return __builtin_amdgcn_sqrtf(x); }
__device__ __forceinline__ float fast_log(float x)  { return __builtin_amdgcn_logf(x) * 0.69314718056f; }

#define JACOBI_ROT(app, aqq, apq, arp, arq, vp0, vq0, vp1, vq1, vp2, vq2)      \
  do {                                                                         \
    float _apq = apq;                                                          \
    float _tau = (aqq - app) * 0.5f * fast_rcp(_apq);                          \
    float _t = copysignf(fast_rcp(fabsf(_tau) + fast_sqrt(fmaf(_tau, _tau, 1.f))), _tau); \
    _t = (fabsf(_apq) > 1e-20f) ? _t : 0.f;                                    \
    float _c = fast_rsq(fmaf(_t, _t, 1.f));                                    \
    float _s = _t * _c;                                                        \
    float _arp = arp, _arq = arq;                                              \
    arp = _c * _arp - _s * _arq;                                               \
    arq = _s * _arp + _c * _arq;                                               \
    app = fmaf(-_t, _apq, app);                                                \
    aqq = fmaf(_t, _apq, aqq);                                                 \
    apq = 0.f;                                                                 \
    float _v;                                                                  \
    _v = vp0; vp0 = _c * _v - _s * vq0; vq0 = _s * _v + _c * vq0;              \
    _v = vp1; vp1 = _c * _v - _s * vq1; vq1 = _s * _v + _c * vq1;              \
    _v = vp2; vp2 = _c * _v - _s * vq2; vq2 = _s * _v + _c * vq2;              \
  } while (0)

__global__ __launch_bounds__(64) void spd_encoder_kernel(
    const float* __restrict__ X,
    const float* __restrict__ W1,
    const float* __restrict__ W2,
    const float* __restrict__ W3,
    float* __restrict__ out)
{
    __shared__ float sX[2592];   // 32 matrices * 81 floats = 10368 B
    __shared__ float sM[27];     // M = W1@W2@W3, 9x3 row-major

    const int lane = threadIdx.x;                      // 0..63
    const long long base = (long long)blockIdx.x * 32; // first matrix index

    // ---- async global->LDS staging (issued first; HBM fetch starts now) ----
    // tile = 10368 B: 10 x width-16 full-wave + 1 x width-16 on lanes 0..7
    {
        GLOBAL_AS const float* g = (GLOBAL_AS const float*)(X + base * 81);
        #pragma unroll
        for (int k = 0; k < 10; ++k)
            __builtin_amdgcn_global_load_lds(
                (GLOBAL_AS const void*)(g + k * 256 + lane * 4),
                (LDS_AS void*)(sX + k * 256), 16, 0, 0);
        if (lane < 8)
            __builtin_amdgcn_global_load_lds(
                (GLOBAL_AS const void*)(g + 2560 + lane * 4),
                (LDS_AS void*)(sX + 2560), 16, 0, 0);
    }

    // ---- M = W1(9x7)@W2(7x5)@W3(5x3), lanes 0..26 (overlaps the fetch) ----
    if (lane < 27) {
        const int i = lane / 3, c = lane % 3;
        float acc = 0.f;
        #pragma unroll
        for (int a = 0; a < 7; ++a) {
            float p = 0.f;
            #pragma unroll
            for (int b = 0; b < 5; ++b)
                p = fmaf(W2[a * 5 + b], W3[b * 3 + c], p);
            acc = fmaf(W1[i * 7 + a], p, acc);
        }
        sM[lane] = acc;
    }

    // Single-wave workgroup: no s_barrier needed. Drain the global->LDS DMA
    // (vmcnt) and the sM ds_writes (lgkmcnt); memory clobber stops the
    // compiler from hoisting the sX/sM reads above this point.
    asm volatile("s_waitcnt vmcnt(0) lgkmcnt(0)" ::: "memory");

    if (lane < 32) {
        // ---- per-lane M in registers (broadcast LDS reads) ----
        float M[9][3];
        #pragma unroll
        for (int i = 0; i < 9; ++i)
            #pragma unroll
            for (int c = 0; c < 3; ++c)
                M[i][c] = sM[i * 3 + c];

        // ---- T = X * M (9x3); 32 lanes, stride 81 -> conflict-free ----
        const float* __restrict__ x = sX + lane * 81;
        float T[9][3];
        #pragma unroll
        for (int i = 0; i < 9; ++i) {
            float t0 = 0.f, t1 = 0.f, t2 = 0.f;
            #pragma unroll
            for (int j = 0; j < 9; ++j) {
                const float xv = x[i * 9 + j];
                t0 = fmaf(xv, M[j][0], t0);
                t1 = fmaf(xv, M[j][1], t1);
                t2 = fmaf(xv, M[j][2], t2);
            }
            T[i][0] = t0; T[i][1] = t1; T[i][2] = t2;
        }

        // ---- Y = M^T * T, symmetric 3x3 ----
        float A00 = 0.f, A01 = 0.f, A02 = 0.f, A11 = 0.f, A12 = 0.f, A22 = 0.f;
        #pragma unroll
        for (int i = 0; i < 9; ++i) {
            A00 = fmaf(M[i][0], T[i][0], A00);
            A01 = fmaf(M[i][0], T[i][1], A01);
            A02 = fmaf(M[i][0], T[i][2], A02);
            A11 = fmaf(M[i][1], T[i][1], A11);
            A12 = fmaf(M[i][1], T[i][2], A12);
            A22 = fmaf(M[i][2], T[i][2], A22);
        }

        // ---- Jacobi eig (5 cyclic sweeps, fully unrolled) ----
        float V00 = 1.f, V01 = 0.f, V02 = 0.f;
        float V10 = 0.f, V11 = 1.f, V12 = 0.f;
        float V20 = 0.f, V21 = 0.f, V22 = 1.f;
        #pragma unroll
        for (int sw = 0; sw < 5; ++sw) {
            JACOBI_ROT(A00, A11, A01, A02, A12, V00, V01, V10, V11, V20, V21);
            JACOBI_ROT(A00, A22, A02, A01, A12, V00, V02, V10, V12, V20, V22);
            JACOBI_ROT(A11, A22, A12, A01, A02, V01, V02, V11, V12, V21, V22);
        }

        // ---- L = V diag(log w) V^T ----
        const float lw0 = fast_log(fmaxf(A00, 1e-12f));
        const float lw1 = fast_log(fmaxf(A11, 1e-12f));
        const float lw2 = fast_log(fmaxf(A22, 1e-12f));

        const float L00 = lw0 * V00 * V00 + lw1 * V01 * V01 + lw2 * V02 * V02;
        const float L01 = lw0 * V00 * V10 + lw1 * V01 * V11 + lw2 * V02 * V12;
        const float L02 = lw0 * V00 * V20 + lw1 * V01 * V21 + lw2 * V02 * V22;
        const float L11 = lw0 * V10 * V10 + lw1 * V11 * V11 + lw2 * V12 * V12;
        const float L12 = lw0 * V10 * V20 + lw1 * V11 * V21 + lw2 * V12 * V22;
        const float L22 = lw0 * V20 * V20 + lw1 * V21 * V21 + lw2 * V22 * V22;

        // ---- vech upper triangle: (0,0),(0,1),(0,2),(1,1),(1,2),(2,2) ----
        float2* o2 = (float2*)(out + (base + lane) * 6);  // 24B stride, 8B aligned
        o2[0] = make_float2(L00, L01);
        o2[1] = make_float2(L02, L11);
        o2[2] = make_float2(L12, L22);
    }
}

extern "C" void kernel_launch(void* const* d_in, const int* in_sizes, int n_in,
                              void* d_out, int out_size, void* d_ws, size_t ws_size,
                              hipStream_t stream) {
    const float* X  = (const float*)d_in[0];
    const float* W1 = (const float*)d_in[1];
    const float* W2 = (const float*)d_in[2];
    const float* W3 = (const float*)d_in[3];
    float* out = (float*)d_out;

    const int B = in_sizes[0] / 81;        // 524288
    const int nblocks = B / 32;            // 16384 one-wave blocks
    spd_encoder_kernel<<<nblocks, 64, 0, stream>>>(X, W1, W2, W3, out);
}